// Round 3
// baseline (180.870 us; speedup 1.0000x reference)
//
#include <hip/hip_runtime.h>
#include <hip/hip_bf16.h>

typedef __bf16 bf16x8 __attribute__((ext_vector_type(8)));
typedef float f32x4 __attribute__((ext_vector_type(4)));

#define MFMA(a, b, c) __builtin_amdgcn_mfma_f32_16x16x32_bf16((a), (b), (c), 0, 0, 0)

static constexpr int T_LEN = 2048;
static constexpr int C_DIM = 1024;
static constexpr int H_DIM = 128;
static constexpr int M_ROWS = 8 * 2048;    // 16384
static constexpr int N_COLS = 384;         // 3 * 128

__device__ __forceinline__ ushort f2bf(float f) {
  union { float f; unsigned u; } v; v.f = f;
  unsigned u = v.u;
  u += 0x7fffu + ((u >> 16) & 1u);
  return (ushort)(u >> 16);
}
__device__ __forceinline__ float bf2f(ushort u) {
  union { unsigned u; float f; } v; v.u = (unsigned)u << 16;
  return v.f;
}

// ---------------------------------------------------------------------------
// Kernel 0: Wq/Wk/Wv fp32 [1024][128] -> bf16 Wt[384][1024] (transposed)
// ---------------------------------------------------------------------------
__global__ void wt_convert(const float* __restrict__ Wq,
                           const float* __restrict__ Wk,
                           const float* __restrict__ Wv,
                           ushort* __restrict__ wt) {
  int flat = blockIdx.x * 256 + threadIdx.x;
  int gc = flat >> 10;
  int c  = flat & 1023;
  int mat = gc >> 7;
  int h   = gc & 127;
  const float* W = (mat == 0) ? Wq : ((mat == 1) ? Wk : Wv);
  wt[flat] = f2bf(W[c * H_DIM + h]);
}

// ---------------------------------------------------------------------------
// Kernel 1: fused QKV projection, BARRIER-FREE. 512 blocks, 32-row tiles.
// All 4 waves share the same A rows (L1 hits); A-frags loaded direct from
// global fp32 and converted in-register. No LDS, no __syncthreads.
// ---------------------------------------------------------------------------
__global__ __launch_bounds__(256, 4) void qkv_gemm(const float* __restrict__ X,
                                                   const ushort* __restrict__ wt,
                                                   ushort* __restrict__ qws,
                                                   ushort* __restrict__ kws,
                                                   ushort* __restrict__ vtws) {
  const int tid = threadIdx.x;
  const int wid = tid >> 6, lane = tid & 63;
  const int lg = lane >> 4, lr = lane & 15;
  const int m0 = blockIdx.x * 32;

  f32x4 acc[2][6];
#pragma unroll
  for (int r = 0; r < 2; ++r)
#pragma unroll
    for (int c = 0; c < 6; ++c)
      acc[r][c] = f32x4{0.f, 0.f, 0.f, 0.f};

#pragma unroll 2
  for (int kt = 0; kt < 32; ++kt) {
    bf16x8 a[2];
#pragma unroll
    for (int r = 0; r < 2; ++r) {
      const float* xp = &X[(size_t)(m0 + r * 16 + lr) * C_DIM + kt * 32 + lg * 8];
      float4 x0 = *(const float4*)xp;
      float4 x1 = *(const float4*)(xp + 4);
      bf16x8 av;
      av[0] = (__bf16)x0.x; av[1] = (__bf16)x0.y; av[2] = (__bf16)x0.z; av[3] = (__bf16)x0.w;
      av[4] = (__bf16)x1.x; av[5] = (__bf16)x1.y; av[6] = (__bf16)x1.z; av[7] = (__bf16)x1.w;
      a[r] = av;
    }
#pragma unroll
    for (int c = 0; c < 6; ++c) {
      int gc = wid * 96 + c * 16 + lr;
      bf16x8 bfrag = *(const bf16x8*)&wt[(size_t)gc * C_DIM + kt * 32 + lg * 8];
      acc[0][c] = MFMA(a[0], bfrag, acc[0][c]);
      acc[1][c] = MFMA(a[1], bfrag, acc[1][c]);
    }
  }

  // epilogue: C frag layout col=lane&15, row=(lane>>4)*4+j
#pragma unroll
  for (int c = 0; c < 6; ++c) {
    int gc = wid * 96 + c * 16 + lr;
    int mat = gc >> 7, h = gc & 127;
#pragma unroll
    for (int r = 0; r < 2; ++r) {
#pragma unroll
      for (int j = 0; j < 4; ++j) {
        int gr = m0 + r * 16 + lg * 4 + j;
        ushort ov = f2bf(acc[r][c][j]);
        if (mat == 0) {
          qws[(size_t)gr * H_DIM + h] = ov;
        } else if (mat == 1) {
          kws[(size_t)gr * H_DIM + h] = ov;
        } else {
          int b = gr >> 11, t = gr & 2047;
          vtws[((size_t)b * H_DIM + h) * T_LEN + t] = ov;
        }
      }
    }
  }
}

// ---------------------------------------------------------------------------
// Kernel 2a: flash-decoding partial pass.
// Work item = (b, qi, ck): 16 q rows x chunk of 8 kv tiles; wave w does
// tiles ck*8+w and ck*8+w+4 (those < nt). Uniform load -> full occupancy.
// Grid 8*128*4 = 4096 (empty chunks early-exit; ~2560 real blocks).
// Writes block-merged partial (m,l fp32; acc bf16) to workspace.
// ---------------------------------------------------------------------------
__global__ __launch_bounds__(256, 4) void attn_part(const ushort* __restrict__ qws,
                                                    const ushort* __restrict__ kws,
                                                    const ushort* __restrict__ vtws,
                                                    float* __restrict__ pml,
                                                    ushort* __restrict__ pacc) {
  __shared__ ushort Pl[4][16][72];
  __shared__ float Macc[16][128];
  __shared__ float Sm[4][16], Sl[4][16];

  const int tid = threadIdx.x;
  const int wid = tid >> 6, lane = tid & 63;
  const int lg = lane >> 4, lr = lane & 15;
  const int bid = blockIdx.x;
  const int b  = bid & 7;              // XCD spread: batch pinned per XCD
  const int qi = (bid >> 3) & 127;
  const int ck = bid >> 10;
  const int nt  = (qi >> 2) + 1;       // causal kv tiles for this q tile
  const int nch = (qi >> 5) + 1;       // ceil(nt/8)
  if (ck >= nch) return;
  const int q0 = qi * 16;
  const size_t tokbase = (size_t)b * T_LEN;

  bf16x8 qf[4];
#pragma unroll
  for (int hk = 0; hk < 4; ++hk)
    qf[hk] = *(const bf16x8*)&qws[(tokbase + q0 + lr) * H_DIM + hk * 32 + lg * 8];

  f32x4 acc[8];
#pragma unroll
  for (int hf = 0; hf < 8; ++hf) acc[hf] = f32x4{0.f, 0.f, 0.f, 0.f};
  float mrun[4], lrun[4];
#pragma unroll
  for (int j = 0; j < 4; ++j) { mrun[j] = -INFINITY; lrun[j] = 0.f; }

  const float SCL = 0.03125f * 1.44269504f;   // C^-0.5 folded with log2(e)
  const ushort* vb = vtws + (size_t)b * H_DIM * T_LEN;

#pragma unroll
  for (int ti = 0; ti < 2; ++ti) {
    const int kvt = ck * 8 + wid + ti * 4;
    if (kvt >= nt) break;
    const int kv0 = kvt * 64;

    // S = Q K^T
    f32x4 s[4];
#pragma unroll
    for (int c = 0; c < 4; ++c) {
      f32x4 sc = f32x4{0.f, 0.f, 0.f, 0.f};
#pragma unroll
      for (int hk = 0; hk < 4; ++hk) {
        bf16x8 kf = *(const bf16x8*)&kws[(tokbase + kv0 + c * 16 + lr) * H_DIM + hk * 32 + lg * 8];
        sc = MFMA(qf[hk], kf, sc);
      }
      s[c] = sc;
    }

    if (kvt == nt - 1) {
#pragma unroll
      for (int c = 0; c < 4; ++c)
#pragma unroll
        for (int j = 0; j < 4; ++j) {
          int kv = kv0 + c * 16 + lr;
          int qr = q0 + lg * 4 + j;
          s[c][j] = (kv <= qr) ? s[c][j] * SCL : -INFINITY;
        }
    } else {
#pragma unroll
      for (int c = 0; c < 4; ++c)
#pragma unroll
        for (int j = 0; j < 4; ++j) s[c][j] *= SCL;
    }

    float mx[4];
#pragma unroll
    for (int j = 0; j < 4; ++j)
      mx[j] = fmaxf(fmaxf(s[0][j], s[1][j]), fmaxf(s[2][j], s[3][j]));
#pragma unroll
    for (int off = 8; off >= 1; off >>= 1)
#pragma unroll
      for (int j = 0; j < 4; ++j)
        mx[j] = fmaxf(mx[j], __shfl_xor(mx[j], off));

    float mnew[4], scold[4];
#pragma unroll
    for (int j = 0; j < 4; ++j) {
      mnew[j] = fmaxf(mrun[j], mx[j]);
      scold[j] = exp2f(mrun[j] - mnew[j]);
    }

    float rsum[4] = {0.f, 0.f, 0.f, 0.f};
#pragma unroll
    for (int c = 0; c < 4; ++c)
#pragma unroll
      for (int j = 0; j < 4; ++j) {
        float p = exp2f(s[c][j] - mnew[j]);
        rsum[j] += p;
        Pl[wid][lg * 4 + j][c * 16 + lr] = f2bf(p);
      }
#pragma unroll
    for (int off = 8; off >= 1; off >>= 1)
#pragma unroll
      for (int j = 0; j < 4; ++j) rsum[j] += __shfl_xor(rsum[j], off);

#pragma unroll
    for (int j = 0; j < 4; ++j) {
      lrun[j] = lrun[j] * scold[j] + rsum[j];
      mrun[j] = mnew[j];
    }
#pragma unroll
    for (int hf = 0; hf < 8; ++hf)
#pragma unroll
      for (int j = 0; j < 4; ++j) acc[hf][j] *= scold[j];

    bf16x8 pa[2];
#pragma unroll
    for (int f = 0; f < 2; ++f)
      pa[f] = *(const bf16x8*)&Pl[wid][lr][f * 32 + lg * 8];

#pragma unroll
    for (int hf = 0; hf < 8; ++hf) {
#pragma unroll
      for (int f = 0; f < 2; ++f) {
        bf16x8 vf = *(const bf16x8*)&vb[(size_t)(hf * 16 + lr) * T_LEN + kv0 + f * 32 + lg * 8];
        acc[hf] = MFMA(pa[f], vf, acc[hf]);
      }
    }
  }

  // ---- merge the 4 waves' partial (m, l, acc); write partial to ws ----
  if (lr == 0) {
#pragma unroll
    for (int j = 0; j < 4; ++j) {
      Sm[wid][lg * 4 + j] = mrun[j];
      Sl[wid][lg * 4 + j] = lrun[j];
    }
  }
  __syncthreads();

  float mg[4], ltv[4];
#pragma unroll
  for (int j = 0; j < 4; ++j) {
    int r = lg * 4 + j;
    mg[j] = fmaxf(fmaxf(Sm[0][r], Sm[1][r]), fmaxf(Sm[2][r], Sm[3][r]));
    ltv[j] = Sl[0][r] * exp2f(Sm[0][r] - mg[j]) + Sl[1][r] * exp2f(Sm[1][r] - mg[j])
           + Sl[2][r] * exp2f(Sm[2][r] - mg[j]) + Sl[3][r] * exp2f(Sm[3][r] - mg[j]);
    float sc = exp2f(mrun[j] - mg[j]);   // -inf (empty wave) -> 0
#pragma unroll
    for (int hf = 0; hf < 8; ++hf) acc[hf][j] *= sc;
  }

  if (wid == 1) {
#pragma unroll
    for (int hf = 0; hf < 8; ++hf)
#pragma unroll
      for (int j = 0; j < 4; ++j)
        Macc[lg * 4 + j][hf * 16 + lr] = acc[hf][j];
  }
  __syncthreads();
  if (wid == 2) {
#pragma unroll
    for (int hf = 0; hf < 8; ++hf)
#pragma unroll
      for (int j = 0; j < 4; ++j)
        Macc[lg * 4 + j][hf * 16 + lr] += acc[hf][j];
  }
  __syncthreads();
  if (wid == 3) {
#pragma unroll
    for (int hf = 0; hf < 8; ++hf)
#pragma unroll
      for (int j = 0; j < 4; ++j)
        Macc[lg * 4 + j][hf * 16 + lr] += acc[hf][j];
  }
  __syncthreads();
  if (wid == 0) {
    const size_t sidx = ((size_t)(b * 128 + qi)) * 4 + ck;
#pragma unroll
    for (int j = 0; j < 4; ++j) {
      int r = lg * 4 + j;
      if (lr == 0) {
        pml[sidx * 32 + r] = mg[j];
        pml[sidx * 32 + 16 + r] = ltv[j];
      }
#pragma unroll
      for (int hf = 0; hf < 8; ++hf)
        pacc[sidx * 2048 + (size_t)r * 128 + hf * 16 + lr] =
            f2bf(acc[hf][j] + Macc[r][hf * 16 + lr]);
    }
  }
}

// ---------------------------------------------------------------------------
// Kernel 2b: merge <=4 partials per (b, qi) -> fp32 out. 1024 blocks.
// Thread -> (row=tid>>4, 8 cols at (tid&15)*8).
// ---------------------------------------------------------------------------
__global__ __launch_bounds__(256) void attn_merge(const float* __restrict__ pml,
                                                  const ushort* __restrict__ pacc,
                                                  float* __restrict__ out) {
  const int bid = blockIdx.x;
  const int b = bid & 7, qi = bid >> 3;
  const int nch = (qi >> 5) + 1;
  const int tid = threadIdx.x;
  const int r = tid >> 4, c0 = (tid & 15) * 8;
  const size_t sbase = ((size_t)(b * 128 + qi)) * 4;

  float m[4], l[4];
  float mgl = -INFINITY;
  for (int ck = 0; ck < nch; ++ck) {
    m[ck] = pml[(sbase + ck) * 32 + r];
    l[ck] = pml[(sbase + ck) * 32 + 16 + r];
    mgl = fmaxf(mgl, m[ck]);
  }
  float o[8];
#pragma unroll
  for (int i = 0; i < 8; ++i) o[i] = 0.f;
  float L = 0.f;
  for (int ck = 0; ck < nch; ++ck) {
    float w = exp2f(m[ck] - mgl);
    L += l[ck] * w;
    const ushort* ap = &pacc[(sbase + ck) * 2048 + (size_t)r * 128 + c0];
    ushort4 u0 = *(const ushort4*)ap;
    ushort4 u1 = *(const ushort4*)(ap + 4);
    o[0] += w * bf2f(u0.x); o[1] += w * bf2f(u0.y);
    o[2] += w * bf2f(u0.z); o[3] += w * bf2f(u0.w);
    o[4] += w * bf2f(u1.x); o[5] += w * bf2f(u1.y);
    o[6] += w * bf2f(u1.z); o[7] += w * bf2f(u1.w);
  }
  float invL = 1.0f / L;
  float4 r0 = make_float4(o[0] * invL, o[1] * invL, o[2] * invL, o[3] * invL);
  float4 r1 = make_float4(o[4] * invL, o[5] * invL, o[6] * invL, o[7] * invL);
  float* op = &out[((size_t)b * T_LEN + qi * 16 + r) * H_DIM + c0];
  *(float4*)op = r0;
  *(float4*)(op + 4) = r1;
}

// ---------------------------------------------------------------------------
extern "C" void kernel_launch(void* const* d_in, const int* in_sizes, int n_in,
                              void* d_out, int out_size, void* d_ws, size_t ws_size,
                              hipStream_t stream) {
  const float* emb = (const float*)d_in[0];
  const float* Wq  = (const float*)d_in[1];
  const float* Wk  = (const float*)d_in[2];
  const float* Wv  = (const float*)d_in[3];
  float* out = (float*)d_out;

  ushort* wt   = (ushort*)d_ws;                       // [384][1024] bf16
  ushort* qws  = wt  + (size_t)N_COLS * C_DIM;        // [16384][128] bf16
  ushort* kws  = qws + (size_t)M_ROWS * H_DIM;        // [16384][128] bf16
  ushort* vtws = kws + (size_t)M_ROWS * H_DIM;        // [8][128][2048] bf16
  float*  pml  = (float*)(vtws + (size_t)8 * H_DIM * T_LEN);  // [4096][32] f32
  ushort* pacc = (ushort*)(pml + (size_t)4096 * 32);          // [4096][2048] bf16

  wt_convert<<<(N_COLS * C_DIM) / 256, 256, 0, stream>>>(Wq, Wk, Wv, wt);
  qkv_gemm<<<M_ROWS / 32, 256, 0, stream>>>(emb, wt, qws, kws, vtws);
  attn_part<<<8 * 128 * 4, 256, 0, stream>>>(qws, kws, vtws, pml, pacc);
  attn_merge<<<1024, 256, 0, stream>>>(pml, pacc, out);
}

// Round 4
// 146.775 us; speedup vs baseline: 1.2323x; 1.2323x over previous
//
#include <hip/hip_runtime.h>
#include <hip/hip_bf16.h>

typedef __bf16 bf16x8 __attribute__((ext_vector_type(8)));
typedef float f32x4 __attribute__((ext_vector_type(4)));

#define MFMA(a, b, c) __builtin_amdgcn_mfma_f32_16x16x32_bf16((a), (b), (c), 0, 0, 0)

static constexpr int T_LEN = 2048;
static constexpr int C_DIM = 1024;
static constexpr int H_DIM = 128;
static constexpr int M_ROWS = 8 * 2048;    // 16384
static constexpr int N_COLS = 384;         // 3 * 128

__device__ __forceinline__ ushort f2bf(float f) {
  union { float f; unsigned u; } v; v.f = f;
  unsigned u = v.u;
  u += 0x7fffu + ((u >> 16) & 1u);
  return (ushort)(u >> 16);
}
__device__ __forceinline__ float bf2f(ushort u) {
  union { unsigned u; float f; } v; v.u = (unsigned)u << 16;
  return v.f;
}

// ---------------------------------------------------------------------------
// Kernel 0: Wq/Wk/Wv fp32 [1024][128] -> bf16 Wt[384][1024] (transposed)
// ---------------------------------------------------------------------------
__global__ void wt_convert(const float* __restrict__ Wq,
                           const float* __restrict__ Wk,
                           const float* __restrict__ Wv,
                           ushort* __restrict__ wt) {
  int flat = blockIdx.x * 256 + threadIdx.x;
  int gc = flat >> 10;
  int c  = flat & 1023;
  int mat = gc >> 7;
  int h   = gc & 127;
  const float* W = (mat == 0) ? Wq : ((mat == 1) ? Wk : Wv);
  wt[flat] = f2bf(W[c * H_DIM + h]);
}

// ---------------------------------------------------------------------------
// Kernel 1: fused QKV projection. 2-phase double-buffered LDS template.
// 512 thr (8 waves), BM=32, BN=384, BK=64 -> 16 iters, ONE barrier/iter.
// A tile bf16 in LDS, linear [32][128B] + XOR swizzle (row&7)<<4 (T2).
// Wave w owns 48 output cols. Grid 512 -> 2 blocks/CU, 16 waves/CU.
// ---------------------------------------------------------------------------
__global__ __launch_bounds__(512, 4) void qkv_gemm(const float* __restrict__ X,
                                                   const ushort* __restrict__ wt,
                                                   ushort* __restrict__ qws,
                                                   ushort* __restrict__ kws,
                                                   ushort* __restrict__ vtws) {
  __shared__ ushort As[2][32 * 64];   // [buf][row][64 bf16] linear, swizzled
  const int tid = threadIdx.x;
  const int wid = tid >> 6, lane = tid & 63;
  const int lg = lane >> 4, lr = lane & 15;
  const int m0 = blockIdx.x * 32;

  // staging: thread -> (row = tid>>4, 4 floats at col (tid&15)*4)
  const int srow = tid >> 4;
  const int sbyte = ((tid & 15) * 8) ^ ((srow & 7) << 4);   // swizzled byte col
  const float* xrow = &X[(size_t)(m0 + srow) * C_DIM + (tid & 15) * 4];

  f32x4 acc[2][3];
#pragma unroll
  for (int r = 0; r < 2; ++r)
#pragma unroll
    for (int c = 0; c < 3; ++c)
      acc[r][c] = f32x4{0.f, 0.f, 0.f, 0.f};

  // prologue: stage tile 0
  {
    float4 x0 = *(const float4*)&xrow[0];
    ushort4 bv;
    bv.x = f2bf(x0.x); bv.y = f2bf(x0.y); bv.z = f2bf(x0.z); bv.w = f2bf(x0.w);
    *(ushort4*)((char*)&As[0][0] + srow * 128 + sbyte) = bv;
  }

  for (int kt = 0; kt < 16; ++kt) {
    const int cur = kt & 1;
    // issue next-tile global load BEFORE the barrier (latency hides under MFMA)
    float4 xn;
    if (kt < 15) xn = *(const float4*)&xrow[(kt + 1) * 64];

    __syncthreads();   // As[cur] writes (prev iter) visible; frees As[cur^1]

    // A fragments: row = r*16+lr, k-slice ks*32 + lg*8 (bytes: ks*64+lg*16)
    bf16x8 a[2][2];
#pragma unroll
    for (int r = 0; r < 2; ++r)
#pragma unroll
      for (int ks = 0; ks < 2; ++ks) {
        int row = r * 16 + lr;
        int cb = (ks * 64 + lg * 16) ^ ((row & 7) << 4);
        a[r][ks] = *(const bf16x8*)((const char*)&As[cur][0] + row * 128 + cb);
      }

#pragma unroll
    for (int c = 0; c < 3; ++c) {
      int gc = wid * 48 + c * 16 + lr;
#pragma unroll
      for (int ks = 0; ks < 2; ++ks) {
        bf16x8 bfrag = *(const bf16x8*)&wt[(size_t)gc * C_DIM + kt * 64 + ks * 32 + lg * 8];
        acc[0][c] = MFMA(a[0][ks], bfrag, acc[0][c]);
        acc[1][c] = MFMA(a[1][ks], bfrag, acc[1][c]);
      }
    }

    if (kt < 15) {
      ushort4 bv;
      bv.x = f2bf(xn.x); bv.y = f2bf(xn.y); bv.z = f2bf(xn.z); bv.w = f2bf(xn.w);
      *(ushort4*)((char*)&As[cur ^ 1][0] + srow * 128 + sbyte) = bv;
    }
  }

  // epilogue: C frag layout col=lane&15, row=(lane>>4)*4+j
#pragma unroll
  for (int c = 0; c < 3; ++c) {
    int gc = wid * 48 + c * 16 + lr;
    int mat = gc >> 7, h = gc & 127;
#pragma unroll
    for (int r = 0; r < 2; ++r) {
#pragma unroll
      for (int j = 0; j < 4; ++j) {
        int gr = m0 + r * 16 + lg * 4 + j;
        ushort ov = f2bf(acc[r][c][j]);
        if (mat == 0) {
          qws[(size_t)gr * H_DIM + h] = ov;
        } else if (mat == 1) {
          kws[(size_t)gr * H_DIM + h] = ov;
        } else {
          int b = gr >> 11, t = gr & 2047;
          vtws[((size_t)b * H_DIM + h) * T_LEN + t] = ov;
        }
      }
    }
  }
}

// ---------------------------------------------------------------------------
// Kernel 2a: flash-decoding partial pass.
// Work item = (b, qi, ck): 16 q rows x chunk of 8 kv tiles; wave w does
// tiles ck*8+w and ck*8+w+4 (those < nt). Uniform load -> full occupancy.
// ---------------------------------------------------------------------------
__global__ __launch_bounds__(256, 4) void attn_part(const ushort* __restrict__ qws,
                                                    const ushort* __restrict__ kws,
                                                    const ushort* __restrict__ vtws,
                                                    float* __restrict__ pml,
                                                    ushort* __restrict__ pacc) {
  __shared__ ushort Pl[4][16][72];
  __shared__ float Macc[16][128];
  __shared__ float Sm[4][16], Sl[4][16];

  const int tid = threadIdx.x;
  const int wid = tid >> 6, lane = tid & 63;
  const int lg = lane >> 4, lr = lane & 15;
  const int bid = blockIdx.x;
  const int b  = bid & 7;              // XCD spread: batch pinned per XCD
  const int qi = (bid >> 3) & 127;
  const int ck = bid >> 10;
  const int nt  = (qi >> 2) + 1;       // causal kv tiles for this q tile
  const int nch = (qi >> 5) + 1;       // ceil(nt/8)
  if (ck >= nch) return;
  const int q0 = qi * 16;
  const size_t tokbase = (size_t)b * T_LEN;

  bf16x8 qf[4];
#pragma unroll
  for (int hk = 0; hk < 4; ++hk)
    qf[hk] = *(const bf16x8*)&qws[(tokbase + q0 + lr) * H_DIM + hk * 32 + lg * 8];

  f32x4 acc[8];
#pragma unroll
  for (int hf = 0; hf < 8; ++hf) acc[hf] = f32x4{0.f, 0.f, 0.f, 0.f};
  float mrun[4], lrun[4];
#pragma unroll
  for (int j = 0; j < 4; ++j) { mrun[j] = -INFINITY; lrun[j] = 0.f; }

  const float SCL = 0.03125f * 1.44269504f;   // C^-0.5 folded with log2(e)
  const ushort* vb = vtws + (size_t)b * H_DIM * T_LEN;

#pragma unroll
  for (int ti = 0; ti < 2; ++ti) {
    const int kvt = ck * 8 + wid + ti * 4;
    if (kvt >= nt) break;
    const int kv0 = kvt * 64;

    // S = Q K^T
    f32x4 s[4];
#pragma unroll
    for (int c = 0; c < 4; ++c) {
      f32x4 sc = f32x4{0.f, 0.f, 0.f, 0.f};
#pragma unroll
      for (int hk = 0; hk < 4; ++hk) {
        bf16x8 kf = *(const bf16x8*)&kws[(tokbase + kv0 + c * 16 + lr) * H_DIM + hk * 32 + lg * 8];
        sc = MFMA(qf[hk], kf, sc);
      }
      s[c] = sc;
    }

    if (kvt == nt - 1) {
#pragma unroll
      for (int c = 0; c < 4; ++c)
#pragma unroll
        for (int j = 0; j < 4; ++j) {
          int kv = kv0 + c * 16 + lr;
          int qr = q0 + lg * 4 + j;
          s[c][j] = (kv <= qr) ? s[c][j] * SCL : -INFINITY;
        }
    } else {
#pragma unroll
      for (int c = 0; c < 4; ++c)
#pragma unroll
        for (int j = 0; j < 4; ++j) s[c][j] *= SCL;
    }

    float mx[4];
#pragma unroll
    for (int j = 0; j < 4; ++j)
      mx[j] = fmaxf(fmaxf(s[0][j], s[1][j]), fmaxf(s[2][j], s[3][j]));
#pragma unroll
    for (int off = 8; off >= 1; off >>= 1)
#pragma unroll
      for (int j = 0; j < 4; ++j)
        mx[j] = fmaxf(mx[j], __shfl_xor(mx[j], off));

    float mnew[4], scold[4];
#pragma unroll
    for (int j = 0; j < 4; ++j) {
      mnew[j] = fmaxf(mrun[j], mx[j]);
      scold[j] = exp2f(mrun[j] - mnew[j]);
    }

    float rsum[4] = {0.f, 0.f, 0.f, 0.f};
#pragma unroll
    for (int c = 0; c < 4; ++c)
#pragma unroll
      for (int j = 0; j < 4; ++j) {
        float p = exp2f(s[c][j] - mnew[j]);
        rsum[j] += p;
        Pl[wid][lg * 4 + j][c * 16 + lr] = f2bf(p);
      }
#pragma unroll
    for (int off = 8; off >= 1; off >>= 1)
#pragma unroll
      for (int j = 0; j < 4; ++j) rsum[j] += __shfl_xor(rsum[j], off);

#pragma unroll
    for (int j = 0; j < 4; ++j) {
      lrun[j] = lrun[j] * scold[j] + rsum[j];
      mrun[j] = mnew[j];
    }
#pragma unroll
    for (int hf = 0; hf < 8; ++hf)
#pragma unroll
      for (int j = 0; j < 4; ++j) acc[hf][j] *= scold[j];

    bf16x8 pa[2];
#pragma unroll
    for (int f = 0; f < 2; ++f)
      pa[f] = *(const bf16x8*)&Pl[wid][lr][f * 32 + lg * 8];

#pragma unroll
    for (int hf = 0; hf < 8; ++hf) {
#pragma unroll
      for (int f = 0; f < 2; ++f) {
        bf16x8 vf = *(const bf16x8*)&vb[(size_t)(hf * 16 + lr) * T_LEN + kv0 + f * 32 + lg * 8];
        acc[hf] = MFMA(pa[f], vf, acc[hf]);
      }
    }
  }

  // ---- merge the 4 waves' partial (m, l, acc); write partial to ws ----
  if (lr == 0) {
#pragma unroll
    for (int j = 0; j < 4; ++j) {
      Sm[wid][lg * 4 + j] = mrun[j];
      Sl[wid][lg * 4 + j] = lrun[j];
    }
  }
  __syncthreads();

  float mg[4], ltv[4];
#pragma unroll
  for (int j = 0; j < 4; ++j) {
    int r = lg * 4 + j;
    mg[j] = fmaxf(fmaxf(Sm[0][r], Sm[1][r]), fmaxf(Sm[2][r], Sm[3][r]));
    ltv[j] = Sl[0][r] * exp2f(Sm[0][r] - mg[j]) + Sl[1][r] * exp2f(Sm[1][r] - mg[j])
           + Sl[2][r] * exp2f(Sm[2][r] - mg[j]) + Sl[3][r] * exp2f(Sm[3][r] - mg[j]);
    float sc = exp2f(mrun[j] - mg[j]);   // -inf (empty wave) -> 0
#pragma unroll
    for (int hf = 0; hf < 8; ++hf) acc[hf][j] *= sc;
  }

  if (wid == 1) {
#pragma unroll
    for (int hf = 0; hf < 8; ++hf)
#pragma unroll
      for (int j = 0; j < 4; ++j)
        Macc[lg * 4 + j][hf * 16 + lr] = acc[hf][j];
  }
  __syncthreads();
  if (wid == 2) {
#pragma unroll
    for (int hf = 0; hf < 8; ++hf)
#pragma unroll
      for (int j = 0; j < 4; ++j)
        Macc[lg * 4 + j][hf * 16 + lr] += acc[hf][j];
  }
  __syncthreads();
  if (wid == 3) {
#pragma unroll
    for (int hf = 0; hf < 8; ++hf)
#pragma unroll
      for (int j = 0; j < 4; ++j)
        Macc[lg * 4 + j][hf * 16 + lr] += acc[hf][j];
  }
  __syncthreads();
  if (wid == 0) {
    const size_t sidx = ((size_t)(b * 128 + qi)) * 4 + ck;
#pragma unroll
    for (int j = 0; j < 4; ++j) {
      int r = lg * 4 + j;
      if (lr == 0) {
        pml[sidx * 32 + r] = mg[j];
        pml[sidx * 32 + 16 + r] = ltv[j];
      }
#pragma unroll
      for (int hf = 0; hf < 8; ++hf)
        pacc[sidx * 2048 + (size_t)r * 128 + hf * 16 + lr] =
            f2bf(acc[hf][j] + Macc[r][hf * 16 + lr]);
    }
  }
}

// ---------------------------------------------------------------------------
// Kernel 2b: merge <=4 partials per (b, qi) -> fp32 out. 1024 blocks.
// ---------------------------------------------------------------------------
__global__ __launch_bounds__(256) void attn_merge(const float* __restrict__ pml,
                                                  const ushort* __restrict__ pacc,
                                                  float* __restrict__ out) {
  const int bid = blockIdx.x;
  const int b = bid & 7, qi = bid >> 3;
  const int nch = (qi >> 5) + 1;
  const int tid = threadIdx.x;
  const int r = tid >> 4, c0 = (tid & 15) * 8;
  const size_t sbase = ((size_t)(b * 128 + qi)) * 4;

  float m[4], l[4];
  float mgl = -INFINITY;
  for (int ck = 0; ck < nch; ++ck) {
    m[ck] = pml[(sbase + ck) * 32 + r];
    l[ck] = pml[(sbase + ck) * 32 + 16 + r];
    mgl = fmaxf(mgl, m[ck]);
  }
  float o[8];
#pragma unroll
  for (int i = 0; i < 8; ++i) o[i] = 0.f;
  float L = 0.f;
  for (int ck = 0; ck < nch; ++ck) {
    float w = exp2f(m[ck] - mgl);
    L += l[ck] * w;
    const ushort* ap = &pacc[(sbase + ck) * 2048 + (size_t)r * 128 + c0];
    ushort4 u0 = *(const ushort4*)ap;
    ushort4 u1 = *(const ushort4*)(ap + 4);
    o[0] += w * bf2f(u0.x); o[1] += w * bf2f(u0.y);
    o[2] += w * bf2f(u0.z); o[3] += w * bf2f(u0.w);
    o[4] += w * bf2f(u1.x); o[5] += w * bf2f(u1.y);
    o[6] += w * bf2f(u1.z); o[7] += w * bf2f(u1.w);
  }
  float invL = 1.0f / L;
  float4 r0 = make_float4(o[0] * invL, o[1] * invL, o[2] * invL, o[3] * invL);
  float4 r1 = make_float4(o[4] * invL, o[5] * invL, o[6] * invL, o[7] * invL);
  float* op = &out[((size_t)b * T_LEN + qi * 16 + r) * H_DIM + c0];
  *(float4*)op = r0;
  *(float4*)(op + 4) = r1;
}

// ---------------------------------------------------------------------------
extern "C" void kernel_launch(void* const* d_in, const int* in_sizes, int n_in,
                              void* d_out, int out_size, void* d_ws, size_t ws_size,
                              hipStream_t stream) {
  const float* emb = (const float*)d_in[0];
  const float* Wq  = (const float*)d_in[1];
  const float* Wk  = (const float*)d_in[2];
  const float* Wv  = (const float*)d_in[3];
  float* out = (float*)d_out;

  ushort* wt   = (ushort*)d_ws;                       // [384][1024] bf16
  ushort* qws  = wt  + (size_t)N_COLS * C_DIM;        // [16384][128] bf16
  ushort* kws  = qws + (size_t)M_ROWS * H_DIM;        // [16384][128] bf16
  ushort* vtws = kws + (size_t)M_ROWS * H_DIM;        // [8][128][2048] bf16
  float*  pml  = (float*)(vtws + (size_t)8 * H_DIM * T_LEN);  // [4096][32] f32
  ushort* pacc = (ushort*)(pml + (size_t)4096 * 32);          // [4096][2048] bf16

  wt_convert<<<(N_COLS * C_DIM) / 256, 256, 0, stream>>>(Wq, Wk, Wv, wt);
  qkv_gemm<<<M_ROWS / 32, 512, 0, stream>>>(emb, wt, qws, kws, vtws);
  attn_part<<<8 * 128 * 4, 256, 0, stream>>>(qws, kws, vtws, pml, pacc);
  attn_merge<<<1024, 256, 0, stream>>>(pml, pacc, out);
}